// Round 16
// baseline (392.601 us; speedup 1.0000x reference)
//
#include <hip/hip_runtime.h>

typedef unsigned short u16;
typedef unsigned int u32;
typedef __attribute__((ext_vector_type(8))) short bf16x8;
typedef __attribute__((ext_vector_type(4))) float f32x4;
typedef __attribute__((ext_vector_type(2))) unsigned int u32x2;
typedef __attribute__((ext_vector_type(4))) unsigned int u32x4;

__device__ __forceinline__ u16 f2bf(float x){
  unsigned u = __builtin_bit_cast(unsigned, x);
  unsigned r = (u + 0x7FFFu + ((u >> 16) & 1u)) >> 16;   // RNE
  return (u16)r;
}
__device__ __forceinline__ float bf2f(u16 h){
  unsigned u = ((unsigned)h) << 16;
  return __builtin_bit_cast(float, u);
}

__device__ __forceinline__ void gld_lds16(const void* g, void* l){
  __builtin_amdgcn_global_load_lds((const __attribute__((address_space(1))) void*)g,
                                   (__attribute__((address_space(3))) void*)l,
                                   16, 0, 0);
}

// ---------------------------------------------------------------------------
// Weight transpose + bf16 cast, 4 jobs in one dispatch (blockIdx.z).
// ---------------------------------------------------------------------------
__global__ void wconv_kernel(const float* __restrict__ W0, u16* __restrict__ Th0, int K0p,
                             const float* __restrict__ W1, u16* __restrict__ Th1, int K1p,
                             const float* __restrict__ W2, u16* __restrict__ Th2, int K2p,
                             const float* __restrict__ W3, u16* __restrict__ Th3, int K3p)
{
  __shared__ float t[32][33];
  int z = blockIdx.z;
  const float* W = z==0 ? W0 : z==1 ? W1 : z==2 ? W2 : W3;
  u16* Th = z==0 ? Th0 : z==1 ? Th1 : z==2 ? Th2 : Th3;
  int Kpad = z==0 ? K0p : z==1 ? K1p : z==2 ? K2p : K3p;
  int K = (Kpad == 768) ? 729 : 1024;
  int k0 = blockIdx.x * 32;
  if (k0 >= Kpad) return;
  int n0 = blockIdx.y * 32;
  int tx = threadIdx.x & 31, ty = threadIdx.x >> 5;
#pragma unroll
  for (int j = 0; j < 4; j++){
    int k = k0 + ty + j*8;
    float v = (k < K) ? W[(size_t)k*1024 + (n0 + tx)] : 0.f;
    t[ty + j*8][tx] = v;
  }
  __syncthreads();
#pragma unroll
  for (int j = 0; j < 4; j++){
    int n = n0 + ty + j*8;
    int k = k0 + tx;
    size_t idx = (size_t)n*Kpad + k;
    Th[idx] = f2bf(t[tx][ty + j*8]);
  }
}

// ---------------------------------------------------------------------------
// feats, LUT-restructured (R6 form); writes bf16 only.
// ---------------------------------------------------------------------------
__global__ void feats_kernel(const float* __restrict__ x,
                             u16* __restrict__ fh,
                             int row0)
{
  __shared__ float cC[8][28];
  __shared__ float tA[8][81];
  __shared__ float tB[8][12];
  __shared__ float ivk[8];
  const int tid = threadIdx.x;
  const int lrow0 = blockIdx.x * 8;
  if (tid < 8){
    const float* xr = x + (size_t)(row0 + lrow0 + tid) * 18;
    float kk = 1.f;
#pragma unroll
    for (int f = 0; f < 3; f++){
      float xa = xr[3*f+0], xb = xr[3*f+1], xc = xr[3*f+2];
      float ya = xr[9+3*f+0], yb = xr[9+3*f+1], yc = xr[9+3*f+2];
      int bse = f * 9;
      cC[tid][bse+0] = xa*xa + ya*ya;
      cC[tid][bse+1] = xa*xb + ya*yb;
      cC[tid][bse+2] = xa*xc + ya*yc;
      cC[tid][bse+3] = xb*xb + yb*yb;
      cC[tid][bse+4] = xb*xc + yb*yc;
      cC[tid][bse+5] = xc*xc + yc*yc;
      cC[tid][bse+6] = xa*yb - xb*ya;
      cC[tid][bse+7] = xa*yc - xc*ya;
      cC[tid][bse+8] = xb*yc - xc*yb;
      kk *= (xa*xa+ya*ya + xb*xb+yb*yb + xc*xc+yc*yc);
    }
    ivk[tid] = 1.f / kk;
#pragma unroll
    for (int j = 0; j < 6; j++) tB[tid][j] = cC[tid][18+j];
#pragma unroll
    for (int j = 0; j < 3; j++) tB[tid][6+j] = cC[tid][24+j];
  }
  __syncthreads();
#pragma unroll 1
  for (int e = tid; e < 648; e += 256){
    int r = e / 81;
    int k = e - r*81;
    const float* cc = cC[r];
    float val;
    if (k < 36)      {               val =   cc[k/6]     * cc[9  + k%6]; }
    else if (k < 45) { int u = k-36; val = -(cc[6 + u/3] * cc[15 + u%3]); }
    else if (k < 63) { int u = k-45; val =   cc[u/3]     * cc[15 + u%3]; }
    else             { int u = k-63; val = -(cc[6 + u/6] * cc[9  + u%6]); }
    tA[r][k] = val;
  }
  __syncthreads();
#pragma unroll 1
  for (int jj = 0; jj < 3; jj++){
    int o = jj*256 + tid;
    int idxA = 0, idxB = 0; float sgn = 0.f;
    if (o < 270)      {              idxA = o/6;      idxB = o - (o/6)*6; sgn =  1.f; }
    else if (o < 378) { int t = o-270; idxA = 45 + t/3; idxB = 6 + t%3;   sgn = -1.f; }
    else if (o < 513) { int t = o-378; idxA = t/3;      idxB = 6 + t%3;   sgn =  1.f; }
    else if (o < 729) { int t = o-513; idxA = 45 + t/6; idxB = t%6;       sgn = -1.f; }
#pragma unroll
    for (int r = 0; r < 8; r++){
      float v = sgn * tA[r][idxA] * tB[r][idxB] * ivk[r];
      size_t oi = (size_t)(lrow0 + r) * 768 + o;
      fh[oi] = f2bf(v);
    }
  }
}

// ---------------------------------------------------------------------------
// Dual-tower single-layer GEMM, pure bf16 1-pass: C = A*B.
// R13 K-loop (proven best): 256x256 tile, BK=32, 512 threads = 8 waves
// (2m x 4n), wave tile 128x64; 3-buffer pipeline, counted vmcnt(4), ONE
// barrier per K-step, setprio around MFMA cluster.
// Towers merged in one dispatch: wg = mb*8 + tower*4 + nb.
// MODE 0: epilogue (acc+bias)^2 -> bf16, COALESCED via per-wave LDS repack
//         (row stride 68 u16: 2-way banks both phases; 2x16B stores/lane
//          -> 128B contiguous rows; fixes the 2.3x sector amplification).
// MODE 1: epilogue (acc+bias)^2 * W3[col], block-col reduce -> partial.
// LDS: sA[3][256][32] (48KB) + sB[3][256][32] (48KB) + rowsum[4][256] (4KB)
// ---------------------------------------------------------------------------
#define GEMM_SMEM_BYTES (49152*2 + 4096)

#define STAGE(BUF) do{ \
    u16* _a = sA + (BUF)*8192; u16* _b = sB + (BUF)*8192; \
    gld_lds16(gAh0, _a + wave*1024); gld_lds16(gAh1, _a + wave*1024 + 512); \
    gld_lds16(gBh0, _b + wave*1024); gld_lds16(gBh1, _b + wave*1024 + 512); \
    gAh0 += 32; gAh1 += 32; gBh0 += 32; gBh1 += 32; \
  }while(0)

#define BARRIER()  asm volatile("s_barrier" ::: "memory")
#define LGKM0()    asm volatile("s_waitcnt lgkmcnt(0)" ::: "memory")

template<int MODE>
__global__ __launch_bounds__(512, 1) void gemm_k(
    const u16* __restrict__ Aa, const u16* __restrict__ Ab,
    const u16* __restrict__ Ba, const u16* __restrict__ Bb,
    const float* __restrict__ biasa, const float* __restrict__ biasb,
    u16* __restrict__ Oa, u16* __restrict__ Ob,
    const float* __restrict__ W3a_, const float* __restrict__ W3b_,
    float* __restrict__ Pa, float* __restrict__ Pb, int Pstride,
    int K)
{
  extern __shared__ __align__(16) u16 smem[];
  u16* sA = smem;                                  // [3][256][32] = 48 KB
  u16* sB = smem + 24576;                          // [3][256][32] = 48 KB
  float* rowsum = (float*)(smem + 49152);          // [4][256] (MODE 1)

  // bijective XCD swizzle (guarded for tiny grids)
  const int nwg = gridDim.x;
  const int qq = nwg >> 3;
  const int wg = (nwg & 7) ? (int)blockIdx.x
                           : ((blockIdx.x & 7) * qq + (blockIdx.x >> 3));
  const int nb = wg & 3;
  const int tower = (wg >> 2) & 1;
  const int mb = wg >> 3;

  const u16* Ahi = tower ? Ab : Aa;
  const u16* Bhi = tower ? Bb : Ba;
  const float* bias = tower ? biasb : biasa;

  const int tid = threadIdx.x;
  const int wave = tid >> 6, lane = tid & 63;
  const int wm = wave >> 2, wn = wave & 3;    // 2 row-halves x 4 col-quarters

  // staging addressing (rule-21 pair: inverse-swizzled global source, linear LDS)
  const int l4 = lane >> 2, ls = lane & 3;
  const int fsw  = (l4 >> 1) & 3;
  const int koff = ((ls ^ fsw) << 3);

  const u16* gAh0 = Ahi + (size_t)(mb*256 + wave*32 + l4) * K + koff;
  const u16* gAh1 = gAh0 + (size_t)16 * K;
  const u16* gBh0 = Bhi + (size_t)(nb*256 + wave*32 + l4) * K + koff;
  const u16* gBh1 = gBh0 + (size_t)16 * K;

  // fragment addressing (swizzled ds_read)
  const int r16 = lane & 15, g = lane >> 4;
  const int fr   = (r16 >> 1) & 3;
  const int slot = ((g ^ fr) << 3);

  f32x4 acc[8][4];
#pragma unroll
  for (int m = 0; m < 8; m++)
#pragma unroll
    for (int n = 0; n < 4; n++)
      acc[m][n] = (f32x4){0.f, 0.f, 0.f, 0.f};

  const int NT = K >> 5;          // 24 or 32 (always >= 3)
  STAGE(0); STAGE(1);             // 8 loads in flight

#pragma unroll 1
  for (int t = 0; t < NT; ++t){
    if (t + 1 < NT){
      asm volatile("s_waitcnt vmcnt(4)" ::: "memory");
    } else {
      asm volatile("s_waitcnt vmcnt(0)" ::: "memory");
    }
    BARRIER();
    if (t + 2 < NT){
      int b2 = (t + 2) % 3;
      STAGE(b2);
    }
    const int cur = t % 3;
    const u16* pA = sA + cur*8192;
    const u16* pB = sB + cur*8192;
    bf16x8 ah[8], bh[4];
#pragma unroll
    for (int n = 0; n < 4; n++) bh[n] = *(const bf16x8*)(pB + (wn*64 + n*16 + r16)*32 + slot);
#pragma unroll
    for (int m = 0; m < 8; m++) ah[m] = *(const bf16x8*)(pA + (wm*128 + m*16 + r16)*32 + slot);
    __builtin_amdgcn_s_setprio(1);
#pragma unroll
    for (int m = 0; m < 8; m++)
#pragma unroll
      for (int n = 0; n < 4; n++)
        acc[m][n] = __builtin_amdgcn_mfma_f32_16x16x32_bf16(ah[m], bh[n], acc[m][n], 0, 0, 0);
    __builtin_amdgcn_s_setprio(0);
  }

  if constexpr (MODE == 0){
    u16* Oh = tower ? Ob : Oa;
    float bv[4];
#pragma unroll
    for (int n = 0; n < 4; n++) bv[n] = bias[nb*256 + wn*64 + n*16 + r16];
    __syncthreads();                       // all waves done reading K-loop LDS
    // per-wave repack buffer: 16 rows x 68 u16 (136B stride: 2-way banks)
    u16* wbuf = smem + wave*1088;
    const int rr = lane >> 2, c4 = lane & 3;
#pragma unroll 1
    for (int m = 0; m < 8; m++){
#pragma unroll
      for (int n = 0; n < 4; n++)
#pragma unroll
        for (int q = 0; q < 4; q++){
          float val = acc[m][n][q] + bv[n];
          val = val * val;
          wbuf[(g*4 + q)*68 + n*16 + r16] = f2bf(val);
        }
      LGKM0();                             // writes done before own reads
      const u16* rp = wbuf + rr*68 + c4*16;
      u32x2 d0 = *(const u32x2*)(rp);
      u32x2 d1 = *(const u32x2*)(rp + 4);
      u32x2 d2 = *(const u32x2*)(rp + 8);
      u32x2 d3 = *(const u32x2*)(rp + 12);
      size_t grow = (size_t)(mb*256 + wm*128 + m*16 + rr);
      u16* gp = Oh + grow*1024 + nb*256 + wn*64 + c4*16;
      u32x4 s0 = (u32x4){d0[0], d0[1], d1[0], d1[1]};
      u32x4 s1 = (u32x4){d2[0], d2[1], d3[0], d3[1]};
      *(u32x4*)(gp)     = s0;
      *(u32x4*)(gp + 8) = s1;
      LGKM0();                             // reads done before next iter's writes
    }
  } else {
    const float* W3 = tower ? W3b_ : W3a_;
    float* P = tower ? Pb : Pa;
    float w3v[4], bv[4];
#pragma unroll
    for (int n = 0; n < 4; n++){
      int col = nb*256 + wn*64 + n*16 + r16;
      w3v[n] = W3[col];
      bv[n]  = bias[col];
    }
    float rp[8][4];
#pragma unroll
    for (int m = 0; m < 8; m++)
#pragma unroll
      for (int q = 0; q < 4; q++)
        rp[m][q] = 0.f;
#pragma unroll
    for (int m = 0; m < 8; m++)
#pragma unroll
      for (int n = 0; n < 4; n++)
#pragma unroll
        for (int q = 0; q < 4; q++){
          float v = acc[m][n][q] + bv[n];
          rp[m][q] += v * v * w3v[n];
        }
#pragma unroll
    for (int m = 0; m < 8; m++)
#pragma unroll
      for (int q = 0; q < 4; q++){
        float s = rp[m][q];
        s += __shfl_xor(s, 1); s += __shfl_xor(s, 2);
        s += __shfl_xor(s, 4); s += __shfl_xor(s, 8);
        rp[m][q] = s;
      }
    if (r16 == 0){
#pragma unroll
      for (int m = 0; m < 8; m++)
#pragma unroll
        for (int q = 0; q < 4; q++)
          rowsum[wn*256 + wm*128 + m*16 + g*4 + q] = rp[m][q];
    }
    __syncthreads();
    if (tid < 256){
      float s = rowsum[tid] + rowsum[256 + tid] + rowsum[512 + tid] + rowsum[768 + tid];
      P[(size_t)nb * Pstride + mb*256 + tid] = s;
    }
  }
}

// ---------------------------------------------------------------------------
// finalize: a3 = b3 + sum_j partial[j][row]; out = clip(2log|a3a|*Wfa - ..b..)
// ---------------------------------------------------------------------------
__global__ void finalize_kernel(const float* __restrict__ Pa, const float* __restrict__ Pb,
                                int Pstride,
                                const float* __restrict__ b3a, const float* __restrict__ Wfa,
                                const float* __restrict__ b3b, const float* __restrict__ Wfb,
                                float* __restrict__ out, int row0, int Rc)
{
  int r = blockIdx.x * 256 + threadIdx.x;
  if (r >= Rc) return;
  float sa = b3a[0], sb = b3b[0];
#pragma unroll
  for (int j = 0; j < 4; j++){
    sa += Pa[(size_t)j * Pstride + r];
    sb += Pb[(size_t)j * Pstride + r];
  }
  float ta = 2.f * logf(fabsf(sa)) * Wfa[0];
  float tb = 2.f * logf(fabsf(sb)) * Wfb[0];
  float o = ta - tb;
  o = fminf(fmaxf(o, -1000000.f), 1000000.f);
  out[row0 + r] = o;
}

// ---------------------------------------------------------------------------
static inline size_t align256(size_t v){ return (v + 255) & ~(size_t)255; }

extern "C" void kernel_launch(void* const* d_in, const int* in_sizes, int n_in,
                              void* d_out, int out_size, void* d_ws, size_t ws_size,
                              hipStream_t stream)
{
  (void)n_in; (void)out_size;
  const float* x   = (const float*)d_in[0];
  const float* W1a = (const float*)d_in[1];
  const float* b1a = (const float*)d_in[2];
  const float* W2a = (const float*)d_in[3];
  const float* b2a = (const float*)d_in[4];
  const float* W3a = (const float*)d_in[5];
  const float* b3a = (const float*)d_in[6];
  const float* Wfa = (const float*)d_in[7];
  const float* W1b = (const float*)d_in[8];
  const float* b1b = (const float*)d_in[9];
  const float* W2b = (const float*)d_in[10];
  const float* b2b = (const float*)d_in[11];
  const float* W3b = (const float*)d_in[12];
  const float* b3b = (const float*)d_in[13];
  const float* Wfb = (const float*)d_in[14];
  float* out = (float*)d_out;

  const int B  = in_sizes[0] / 18;
  const int K1 = 768;
  const int K2 = 1024;

  hipFuncSetAttribute((const void*)gemm_k<0>,
                      hipFuncAttributeMaxDynamicSharedMemorySize, GEMM_SMEM_BYTES);
  hipFuncSetAttribute((const void*)gemm_k<1>,
                      hipFuncAttributeMaxDynamicSharedMemorySize, GEMM_SMEM_BYTES);

  char* base = (char*)d_ws;
  size_t off = 0;
  auto carve = [&](size_t bytes) -> char* {
    off = align256(off);
    char* p = base + off;
    off += bytes;
    return p;
  };

  u16* wt1a = (u16*)carve((size_t)1024 * K1 * 2);
  u16* wt2a = (u16*)carve((size_t)1024 * K2 * 2);
  u16* wt1b = (u16*)carve((size_t)1024 * K1 * 2);
  u16* wt2b = (u16*)carve((size_t)1024 * K2 * 2);

  size_t fixed = align256(off);
  // per-row live set: feats (1536) + h1a (2048) + h1b (2048) + partials (64)
  const long long per_row = (long long)K1*2 + 4096 + 64;
  long long avail = (long long)ws_size - (long long)fixed - 8192;
  long long rmax = avail > 0 ? avail / per_row : 0;
  int R = (int)((rmax / 256) * 256);
  if (R > B) R = B;
  if (R < 256) R = 256;

  u16* fh   = (u16*)carve((size_t)R * K1 * 2);
  u16* h1a  = (u16*)carve((size_t)R * 1024 * 2);
  u16* h1b  = (u16*)carve((size_t)R * 1024 * 2);
  float* pa = (float*)carve((size_t)4 * R * 4);
  float* pb = (float*)carve((size_t)4 * R * 4);

  // all four weight transposes in one dispatch
  wconv_kernel<<<dim3(32, 32, 4), 256, 0, stream>>>(
      W1a, wt1a, K1,
      W2a, wt2a, K2,
      W1b, wt1b, K1,
      W2b, wt2b, K2);

  for (int row0 = 0; row0 < B; row0 += R){
    int Rc = B - row0; if (Rc > R) Rc = R;
    int MB = Rc / 256;
    feats_kernel<<<Rc/8, 256, 0, stream>>>(x, fh, row0);
    // layer 1, both towers in one dispatch
    gemm_k<0><<<dim3(8*MB), 512, GEMM_SMEM_BYTES, stream>>>(
        fh, fh, wt1a, wt1b, b1a, b1b,
        h1a, h1b, nullptr, nullptr, nullptr, nullptr, 0, K1);
    // layer 2 + dot3, both towers in one dispatch
    gemm_k<1><<<dim3(8*MB), 512, GEMM_SMEM_BYTES, stream>>>(
        h1a, h1b, wt2a, wt2b, b2a, b2b,
        nullptr, nullptr, W3a, W3b, pa, pb, R, K2);
    finalize_kernel<<<(Rc + 255)/256, 256, 0, stream>>>(pa, pb, R, b3a, Wfa, b3b, Wfb,
                                                        out, row0, Rc);
  }
}

// Round 17
// 267.076 us; speedup vs baseline: 1.4700x; 1.4700x over previous
//
#include <hip/hip_runtime.h>

typedef unsigned short u16;
typedef unsigned int u32;
typedef __attribute__((ext_vector_type(8))) short bf16x8;
typedef __attribute__((ext_vector_type(4))) float f32x4;
typedef __attribute__((ext_vector_type(2))) unsigned int u32x2;
typedef __attribute__((ext_vector_type(4))) unsigned int u32x4;

__device__ __forceinline__ u16 f2bf(float x){
  unsigned u = __builtin_bit_cast(unsigned, x);
  unsigned r = (u + 0x7FFFu + ((u >> 16) & 1u)) >> 16;   // RNE
  return (u16)r;
}
__device__ __forceinline__ float bf2f(u16 h){
  unsigned u = ((unsigned)h) << 16;
  return __builtin_bit_cast(float, u);
}

__device__ __forceinline__ void gld_lds16(const void* g, void* l){
  __builtin_amdgcn_global_load_lds((const __attribute__((address_space(1))) void*)g,
                                   (__attribute__((address_space(3))) void*)l,
                                   16, 0, 0);
}

// ---------------------------------------------------------------------------
// Weight transpose + bf16 cast, 4 jobs in one dispatch (blockIdx.z).
// ---------------------------------------------------------------------------
__global__ void wconv_kernel(const float* __restrict__ W0, u16* __restrict__ Th0, int K0p,
                             const float* __restrict__ W1, u16* __restrict__ Th1, int K1p,
                             const float* __restrict__ W2, u16* __restrict__ Th2, int K2p,
                             const float* __restrict__ W3, u16* __restrict__ Th3, int K3p)
{
  __shared__ float t[32][33];
  int z = blockIdx.z;
  const float* W = z==0 ? W0 : z==1 ? W1 : z==2 ? W2 : W3;
  u16* Th = z==0 ? Th0 : z==1 ? Th1 : z==2 ? Th2 : Th3;
  int Kpad = z==0 ? K0p : z==1 ? K1p : z==2 ? K2p : K3p;
  int K = (Kpad == 768) ? 729 : 1024;
  int k0 = blockIdx.x * 32;
  if (k0 >= Kpad) return;
  int n0 = blockIdx.y * 32;
  int tx = threadIdx.x & 31, ty = threadIdx.x >> 5;
#pragma unroll
  for (int j = 0; j < 4; j++){
    int k = k0 + ty + j*8;
    float v = (k < K) ? W[(size_t)k*1024 + (n0 + tx)] : 0.f;
    t[ty + j*8][tx] = v;
  }
  __syncthreads();
#pragma unroll
  for (int j = 0; j < 4; j++){
    int n = n0 + ty + j*8;
    int k = k0 + tx;
    size_t idx = (size_t)n*Kpad + k;
    Th[idx] = f2bf(t[tx][ty + j*8]);
  }
}

// ---------------------------------------------------------------------------
// feats, LUT-restructured (R6 form); writes bf16 only.
// ---------------------------------------------------------------------------
__global__ void feats_kernel(const float* __restrict__ x,
                             u16* __restrict__ fh,
                             int row0)
{
  __shared__ float cC[8][28];
  __shared__ float tA[8][81];
  __shared__ float tB[8][12];
  __shared__ float ivk[8];
  const int tid = threadIdx.x;
  const int lrow0 = blockIdx.x * 8;
  if (tid < 8){
    const float* xr = x + (size_t)(row0 + lrow0 + tid) * 18;
    float kk = 1.f;
#pragma unroll
    for (int f = 0; f < 3; f++){
      float xa = xr[3*f+0], xb = xr[3*f+1], xc = xr[3*f+2];
      float ya = xr[9+3*f+0], yb = xr[9+3*f+1], yc = xr[9+3*f+2];
      int bse = f * 9;
      cC[tid][bse+0] = xa*xa + ya*ya;
      cC[tid][bse+1] = xa*xb + ya*yb;
      cC[tid][bse+2] = xa*xc + ya*yc;
      cC[tid][bse+3] = xb*xb + yb*yb;
      cC[tid][bse+4] = xb*xc + yb*yc;
      cC[tid][bse+5] = xc*xc + yc*yc;
      cC[tid][bse+6] = xa*yb - xb*ya;
      cC[tid][bse+7] = xa*yc - xc*ya;
      cC[tid][bse+8] = xb*yc - xc*yb;
      kk *= (xa*xa+ya*ya + xb*xb+yb*yb + xc*xc+yc*yc);
    }
    ivk[tid] = 1.f / kk;
#pragma unroll
    for (int j = 0; j < 6; j++) tB[tid][j] = cC[tid][18+j];
#pragma unroll
    for (int j = 0; j < 3; j++) tB[tid][6+j] = cC[tid][24+j];
  }
  __syncthreads();
#pragma unroll 1
  for (int e = tid; e < 648; e += 256){
    int r = e / 81;
    int k = e - r*81;
    const float* cc = cC[r];
    float val;
    if (k < 36)      {               val =   cc[k/6]     * cc[9  + k%6]; }
    else if (k < 45) { int u = k-36; val = -(cc[6 + u/3] * cc[15 + u%3]); }
    else if (k < 63) { int u = k-45; val =   cc[u/3]     * cc[15 + u%3]; }
    else             { int u = k-63; val = -(cc[6 + u/6] * cc[9  + u%6]); }
    tA[r][k] = val;
  }
  __syncthreads();
#pragma unroll 1
  for (int jj = 0; jj < 3; jj++){
    int o = jj*256 + tid;
    int idxA = 0, idxB = 0; float sgn = 0.f;
    if (o < 270)      {              idxA = o/6;      idxB = o - (o/6)*6; sgn =  1.f; }
    else if (o < 378) { int t = o-270; idxA = 45 + t/3; idxB = 6 + t%3;   sgn = -1.f; }
    else if (o < 513) { int t = o-378; idxA = t/3;      idxB = 6 + t%3;   sgn =  1.f; }
    else if (o < 729) { int t = o-513; idxA = 45 + t/6; idxB = t%6;       sgn = -1.f; }
#pragma unroll
    for (int r = 0; r < 8; r++){
      float v = sgn * tA[r][idxA] * tB[r][idxB] * ivk[r];
      size_t oi = (size_t)(lrow0 + r) * 768 + o;
      fh[oi] = f2bf(v);
    }
  }
}

// ---------------------------------------------------------------------------
// Dual-tower single-layer GEMM, pure bf16 1-pass: C = A*B.
// R13 K-loop (proven best): 256x256 tile, BK=32, 512 threads = 8 waves
// (2m x 4n), wave tile 128x64; 3-buffer pipeline, counted vmcnt(4), ONE
// barrier per K-step, setprio around MFMA cluster.
// Towers merged in one dispatch: wg = mb*8 + tower*4 + nb.
// MODE 0: epilogue (acc+bias)^2 -> bf16, coalesced via per-wave LDS repack.
//         m-loop FULLY UNROLLED (rule #20: runtime-indexed acc -> scratch;
//         R16's `#pragma unroll 1` demoted acc[8][4] to local memory ->
//         655MB writes, MfmaUtil 17%).
// MODE 1: epilogue (acc+bias)^2 * W3[col], block-col reduce -> partial.
// LDS: sA[3][256][32] (48KB) + sB[3][256][32] (48KB) + rowsum[4][256] (4KB)
// ---------------------------------------------------------------------------
#define GEMM_SMEM_BYTES (49152*2 + 4096)

#define STAGE(BUF) do{ \
    u16* _a = sA + (BUF)*8192; u16* _b = sB + (BUF)*8192; \
    gld_lds16(gAh0, _a + wave*1024); gld_lds16(gAh1, _a + wave*1024 + 512); \
    gld_lds16(gBh0, _b + wave*1024); gld_lds16(gBh1, _b + wave*1024 + 512); \
    gAh0 += 32; gAh1 += 32; gBh0 += 32; gBh1 += 32; \
  }while(0)

#define BARRIER()  asm volatile("s_barrier" ::: "memory")
#define LGKM0()    asm volatile("s_waitcnt lgkmcnt(0)" ::: "memory")

template<int MODE>
__global__ __launch_bounds__(512, 1) void gemm_k(
    const u16* __restrict__ Aa, const u16* __restrict__ Ab,
    const u16* __restrict__ Ba, const u16* __restrict__ Bb,
    const float* __restrict__ biasa, const float* __restrict__ biasb,
    u16* __restrict__ Oa, u16* __restrict__ Ob,
    const float* __restrict__ W3a_, const float* __restrict__ W3b_,
    float* __restrict__ Pa, float* __restrict__ Pb, int Pstride,
    int K)
{
  extern __shared__ __align__(16) u16 smem[];
  u16* sA = smem;                                  // [3][256][32] = 48 KB
  u16* sB = smem + 24576;                          // [3][256][32] = 48 KB
  float* rowsum = (float*)(smem + 49152);          // [4][256] (MODE 1)

  // bijective XCD swizzle (guarded for tiny grids)
  const int nwg = gridDim.x;
  const int qq = nwg >> 3;
  const int wg = (nwg & 7) ? (int)blockIdx.x
                           : ((blockIdx.x & 7) * qq + (blockIdx.x >> 3));
  const int nb = wg & 3;
  const int tower = (wg >> 2) & 1;
  const int mb = wg >> 3;

  const u16* Ahi = tower ? Ab : Aa;
  const u16* Bhi = tower ? Bb : Ba;
  const float* bias = tower ? biasb : biasa;

  const int tid = threadIdx.x;
  const int wave = tid >> 6, lane = tid & 63;
  const int wm = wave >> 2, wn = wave & 3;    // 2 row-halves x 4 col-quarters

  // staging addressing (rule-21 pair: inverse-swizzled global source, linear LDS)
  const int l4 = lane >> 2, ls = lane & 3;
  const int fsw  = (l4 >> 1) & 3;
  const int koff = ((ls ^ fsw) << 3);

  const u16* gAh0 = Ahi + (size_t)(mb*256 + wave*32 + l4) * K + koff;
  const u16* gAh1 = gAh0 + (size_t)16 * K;
  const u16* gBh0 = Bhi + (size_t)(nb*256 + wave*32 + l4) * K + koff;
  const u16* gBh1 = gBh0 + (size_t)16 * K;

  // fragment addressing (swizzled ds_read)
  const int r16 = lane & 15, g = lane >> 4;
  const int fr   = (r16 >> 1) & 3;
  const int slot = ((g ^ fr) << 3);

  f32x4 acc[8][4];
#pragma unroll
  for (int m = 0; m < 8; m++)
#pragma unroll
    for (int n = 0; n < 4; n++)
      acc[m][n] = (f32x4){0.f, 0.f, 0.f, 0.f};

  const int NT = K >> 5;          // 24 or 32 (always >= 3)
  STAGE(0); STAGE(1);             // 8 loads in flight

#pragma unroll 1
  for (int t = 0; t < NT; ++t){
    if (t + 1 < NT){
      asm volatile("s_waitcnt vmcnt(4)" ::: "memory");
    } else {
      asm volatile("s_waitcnt vmcnt(0)" ::: "memory");
    }
    BARRIER();
    if (t + 2 < NT){
      int b2 = (t + 2) % 3;
      STAGE(b2);
    }
    const int cur = t % 3;
    const u16* pA = sA + cur*8192;
    const u16* pB = sB + cur*8192;
    bf16x8 ah[8], bh[4];
#pragma unroll
    for (int n = 0; n < 4; n++) bh[n] = *(const bf16x8*)(pB + (wn*64 + n*16 + r16)*32 + slot);
#pragma unroll
    for (int m = 0; m < 8; m++) ah[m] = *(const bf16x8*)(pA + (wm*128 + m*16 + r16)*32 + slot);
    __builtin_amdgcn_s_setprio(1);
#pragma unroll
    for (int m = 0; m < 8; m++)
#pragma unroll
      for (int n = 0; n < 4; n++)
        acc[m][n] = __builtin_amdgcn_mfma_f32_16x16x32_bf16(ah[m], bh[n], acc[m][n], 0, 0, 0);
    __builtin_amdgcn_s_setprio(0);
  }

  if constexpr (MODE == 0){
    u16* Oh = tower ? Ob : Oa;
    float bv[4];
#pragma unroll
    for (int n = 0; n < 4; n++) bv[n] = bias[nb*256 + wn*64 + n*16 + r16];
    __syncthreads();                       // all waves done reading K-loop LDS
    // per-wave repack buffer: 16 rows x 68 u16 (136B stride: 2-way banks)
    u16* wbuf = smem + wave*1088;
    const int rr = lane >> 2, c4 = lane & 3;
#pragma unroll                             // FULL unroll: static acc indices (rule #20)
    for (int m = 0; m < 8; m++){
#pragma unroll
      for (int n = 0; n < 4; n++)
#pragma unroll
        for (int q = 0; q < 4; q++){
          float val = acc[m][n][q] + bv[n];
          val = val * val;
          wbuf[(g*4 + q)*68 + n*16 + r16] = f2bf(val);
        }
      LGKM0();                             // writes done before own reads
      const u16* rp = wbuf + rr*68 + c4*16;
      u32x2 d0 = *(const u32x2*)(rp);
      u32x2 d1 = *(const u32x2*)(rp + 4);
      u32x2 d2 = *(const u32x2*)(rp + 8);
      u32x2 d3 = *(const u32x2*)(rp + 12);
      size_t grow = (size_t)(mb*256 + wm*128 + m*16 + rr);
      u16* gp = Oh + grow*1024 + nb*256 + wn*64 + c4*16;
      u32x4 s0 = (u32x4){d0[0], d0[1], d1[0], d1[1]};
      u32x4 s1 = (u32x4){d2[0], d2[1], d3[0], d3[1]};
      *(u32x4*)(gp)     = s0;
      *(u32x4*)(gp + 8) = s1;
      LGKM0();                             // reads done before next iter's writes
    }
  } else {
    const float* W3 = tower ? W3b_ : W3a_;
    float* P = tower ? Pb : Pa;
    float w3v[4], bv[4];
#pragma unroll
    for (int n = 0; n < 4; n++){
      int col = nb*256 + wn*64 + n*16 + r16;
      w3v[n] = W3[col];
      bv[n]  = bias[col];
    }
    float rp[8][4];
#pragma unroll
    for (int m = 0; m < 8; m++)
#pragma unroll
      for (int q = 0; q < 4; q++)
        rp[m][q] = 0.f;
#pragma unroll
    for (int m = 0; m < 8; m++)
#pragma unroll
      for (int n = 0; n < 4; n++)
#pragma unroll
        for (int q = 0; q < 4; q++){
          float v = acc[m][n][q] + bv[n];
          rp[m][q] += v * v * w3v[n];
        }
#pragma unroll
    for (int m = 0; m < 8; m++)
#pragma unroll
      for (int q = 0; q < 4; q++){
        float s = rp[m][q];
        s += __shfl_xor(s, 1); s += __shfl_xor(s, 2);
        s += __shfl_xor(s, 4); s += __shfl_xor(s, 8);
        rp[m][q] = s;
      }
    if (r16 == 0){
#pragma unroll
      for (int m = 0; m < 8; m++)
#pragma unroll
        for (int q = 0; q < 4; q++)
          rowsum[wn*256 + wm*128 + m*16 + g*4 + q] = rp[m][q];
    }
    __syncthreads();
    if (tid < 256){
      float s = rowsum[tid] + rowsum[256 + tid] + rowsum[512 + tid] + rowsum[768 + tid];
      P[(size_t)nb * Pstride + mb*256 + tid] = s;
    }
  }
}

// ---------------------------------------------------------------------------
// finalize: a3 = b3 + sum_j partial[j][row]; out = clip(2log|a3a|*Wfa - ..b..)
// ---------------------------------------------------------------------------
__global__ void finalize_kernel(const float* __restrict__ Pa, const float* __restrict__ Pb,
                                int Pstride,
                                const float* __restrict__ b3a, const float* __restrict__ Wfa,
                                const float* __restrict__ b3b, const float* __restrict__ Wfb,
                                float* __restrict__ out, int row0, int Rc)
{
  int r = blockIdx.x * 256 + threadIdx.x;
  if (r >= Rc) return;
  float sa = b3a[0], sb = b3b[0];
#pragma unroll
  for (int j = 0; j < 4; j++){
    sa += Pa[(size_t)j * Pstride + r];
    sb += Pb[(size_t)j * Pstride + r];
  }
  float ta = 2.f * logf(fabsf(sa)) * Wfa[0];
  float tb = 2.f * logf(fabsf(sb)) * Wfb[0];
  float o = ta - tb;
  o = fminf(fmaxf(o, -1000000.f), 1000000.f);
  out[row0 + r] = o;
}

// ---------------------------------------------------------------------------
static inline size_t align256(size_t v){ return (v + 255) & ~(size_t)255; }

extern "C" void kernel_launch(void* const* d_in, const int* in_sizes, int n_in,
                              void* d_out, int out_size, void* d_ws, size_t ws_size,
                              hipStream_t stream)
{
  (void)n_in; (void)out_size;
  const float* x   = (const float*)d_in[0];
  const float* W1a = (const float*)d_in[1];
  const float* b1a = (const float*)d_in[2];
  const float* W2a = (const float*)d_in[3];
  const float* b2a = (const float*)d_in[4];
  const float* W3a = (const float*)d_in[5];
  const float* b3a = (const float*)d_in[6];
  const float* Wfa = (const float*)d_in[7];
  const float* W1b = (const float*)d_in[8];
  const float* b1b = (const float*)d_in[9];
  const float* W2b = (const float*)d_in[10];
  const float* b2b = (const float*)d_in[11];
  const float* W3b = (const float*)d_in[12];
  const float* b3b = (const float*)d_in[13];
  const float* Wfb = (const float*)d_in[14];
  float* out = (float*)d_out;

  const int B  = in_sizes[0] / 18;
  const int K1 = 768;
  const int K2 = 1024;

  hipFuncSetAttribute((const void*)gemm_k<0>,
                      hipFuncAttributeMaxDynamicSharedMemorySize, GEMM_SMEM_BYTES);
  hipFuncSetAttribute((const void*)gemm_k<1>,
                      hipFuncAttributeMaxDynamicSharedMemorySize, GEMM_SMEM_BYTES);

  char* base = (char*)d_ws;
  size_t off = 0;
  auto carve = [&](size_t bytes) -> char* {
    off = align256(off);
    char* p = base + off;
    off += bytes;
    return p;
  };

  u16* wt1a = (u16*)carve((size_t)1024 * K1 * 2);
  u16* wt2a = (u16*)carve((size_t)1024 * K2 * 2);
  u16* wt1b = (u16*)carve((size_t)1024 * K1 * 2);
  u16* wt2b = (u16*)carve((size_t)1024 * K2 * 2);

  size_t fixed = align256(off);
  // per-row live set: feats (1536) + h1a (2048) + h1b (2048) + partials (64)
  const long long per_row = (long long)K1*2 + 4096 + 64;
  long long avail = (long long)ws_size - (long long)fixed - 8192;
  long long rmax = avail > 0 ? avail / per_row : 0;
  int R = (int)((rmax / 256) * 256);
  if (R > B) R = B;
  if (R < 256) R = 256;

  u16* fh   = (u16*)carve((size_t)R * K1 * 2);
  u16* h1a  = (u16*)carve((size_t)R * 1024 * 2);
  u16* h1b  = (u16*)carve((size_t)R * 1024 * 2);
  float* pa = (float*)carve((size_t)4 * R * 4);
  float* pb = (float*)carve((size_t)4 * R * 4);

  // all four weight transposes in one dispatch
  wconv_kernel<<<dim3(32, 32, 4), 256, 0, stream>>>(
      W1a, wt1a, K1,
      W2a, wt2a, K2,
      W1b, wt1b, K1,
      W2b, wt2b, K2);

  for (int row0 = 0; row0 < B; row0 += R){
    int Rc = B - row0; if (Rc > R) Rc = R;
    int MB = Rc / 256;
    feats_kernel<<<Rc/8, 256, 0, stream>>>(x, fh, row0);
    // layer 1, both towers in one dispatch
    gemm_k<0><<<dim3(8*MB), 512, GEMM_SMEM_BYTES, stream>>>(
        fh, fh, wt1a, wt1b, b1a, b1b,
        h1a, h1b, nullptr, nullptr, nullptr, nullptr, 0, K1);
    // layer 2 + dot3, both towers in one dispatch
    gemm_k<1><<<dim3(8*MB), 512, GEMM_SMEM_BYTES, stream>>>(
        h1a, h1b, wt2a, wt2b, b2a, b2b,
        nullptr, nullptr, W3a, W3b, pa, pb, R, K2);
    finalize_kernel<<<(Rc + 255)/256, 256, 0, stream>>>(pa, pb, R, b3a, Wfa, b3b, Wfb,
                                                        out, row0, Rc);
  }
}